// Round 11
// baseline (241.847 us; speedup 1.0000x reference)
//
#include <hip/hip_runtime.h>
#include <stdint.h>

#define GRAPHS 256
#define NPG    512
#define EPG    8192
#define NTOT   (GRAPHS*NPG)

typedef __attribute__((ext_vector_type(8))) short s16x8;
typedef __attribute__((ext_vector_type(4))) float f32x4;

__device__ __forceinline__ float bf2f(unsigned short u){
  union { unsigned int i; float f; } c; c.i = ((unsigned int)u)<<16; return c.f;
}
__device__ __forceinline__ unsigned short f2bf(float f){
  union { float f; unsigned int i; } c; c.f = f;
  unsigned int r = c.i + 0x7fffu + ((c.i>>16)&1u);   // RNE
  return (unsigned short)(r>>16);
}

// ---------- prep: EW1 = emb@W1 in both layouts ------------------------------
__global__ __launch_bounds__(256) void k_prep(const float* __restrict__ emb,
      const float* __restrict__ W1, unsigned short* __restrict__ EW1T,
      unsigned short* __restrict__ EW1R){
  const int gid = blockIdx.x*256 + threadIdx.x;   // 8192 = 64*128
  const int t = gid>>7, c = gid&127;
  float acc=0.f;
  #pragma unroll 4
  for (int k=0;k<128;k++) acc += emb[t*128+k]*W1[k*128+c];
  const unsigned short v = f2bf(acc);
  EW1T[c*64+t]=v;           // [c][t]
  EW1R[t*128+c]=v;          // [t][c]
}

// ---------- degrees + B1T build (one block per graph) -----------------------
// B1T[(b*128+c)*512 + s] = bf16( out_isqrt[s] * EW1[t[s]][c] )
__global__ __launch_bounds__(512) void k_deg(const int* __restrict__ src,
      const int* __restrict__ dst, const int* __restrict__ ntype,
      const unsigned short* __restrict__ EW1R, float* __restrict__ out_isqrt,
      float* __restrict__ in_isqrt, unsigned short* __restrict__ B1T){
  __shared__ int hist[NPG], co[NPG];
  __shared__ unsigned short tsh[NPG];
  __shared__ float wscs[NPG];
  const int b=blockIdx.x, tid=threadIdx.x, eb=b*EPG, nb=b*NPG;
  hist[tid]=0; co[tid]=0;
  if (tid<NPG-512){} // NPG==512, one elem per thread
  tsh[tid]=(unsigned short)ntype[nb+tid];
  __syncthreads();
  const int4* dv = (const int4*)(dst+eb);
  const int4* sv = (const int4*)(src+eb);
  #pragma unroll
  for (int j=0;j<4;j++){
    int4 d4 = dv[tid + j*512];
    int4 s4 = sv[tid + j*512];
    atomicAdd(&hist[d4.x&(NPG-1)],1); atomicAdd(&hist[d4.y&(NPG-1)],1);
    atomicAdd(&hist[d4.z&(NPG-1)],1); atomicAdd(&hist[d4.w&(NPG-1)],1);
    atomicAdd(&co[s4.x&(NPG-1)],1);   atomicAdd(&co[s4.y&(NPG-1)],1);
    atomicAdd(&co[s4.z&(NPG-1)],1);   atomicAdd(&co[s4.w&(NPG-1)],1);
  }
  __syncthreads();
  {
    int a=co[tid]; if(a<1)a=1;
    int c=hist[tid]; if(c<1)c=1;
    const float w = rsqrtf((float)a);
    wscs[tid]=w;
    out_isqrt[nb+tid]=w;
    in_isqrt[nb+tid]=rsqrtf((float)c);
  }
  __syncthreads();
  // B1T: s = tid; read EW1R row t (16 uint4), scale, store column-major.
  const int s = tid;
  const int t = tsh[s];
  const float w = wscs[s];
  const uint4* er = (const uint4*)(EW1R + t*128);
  unsigned short* bp = B1T + (size_t)(b*128)*512 + s;
  #pragma unroll
  for (int jj=0;jj<16;jj++){
    uint4 q = er[jj];
    unsigned int ws[4] = {q.x,q.y,q.z,q.w};
    #pragma unroll
    for (int h=0;h<4;h++){
      const int c = jj*8 + h*2;
      bp[(size_t)c*512]     = f2bf(bf2f((unsigned short)(ws[h]&0xffffu))*w);
      bp[(size_t)(c+1)*512] = f2bf(bf2f((unsigned short)(ws[h]>>16))*w);
    }
  }
}

// ---------- unified aggregation: C(u8 counts) @ feat via MFMA ---------------
// block = (graph, 128-dst tile), 512 thr, ~68 KB LDS -> 2 blocks/CU.
// L==1: feat=B1T; epi: relu(acc*isq+b1)*osc -> h1T[(b*128+col)*512+row] (ushort4)
// L==2: feat=h1T; epi: acc*isq -> M1[row*128+col]
#define AGG_LDS 68096  // A u8[128][520]=66560 | isqs 512 | oscs 512 | bsh 512
template<int L>
__global__ __launch_bounds__(512) void k_agg(const int* __restrict__ src,
      const int* __restrict__ dst, const unsigned short* __restrict__ feat,
      const float* __restrict__ in_isqrt, const float* __restrict__ out_isqrt,
      const float* __restrict__ bias, unsigned short* __restrict__ outp){
  extern __shared__ char smem[];
  unsigned char* A   = (unsigned char*)smem;     // [128][520]
  unsigned int*  A32 = (unsigned int*)smem;
  float* isqs = (float*)(smem + 66560);          // [128]
  float* oscs = (float*)(smem + 67072);          // [128]
  float* bsh  = (float*)(smem + 67584);          // [128]
  const int bid=blockIdx.x;
  const int b  = ((bid>>5)<<3) | (bid&7);        // graph (XCD swizzle)
  const int dt = (bid>>3)&3;                     // dst tile
  const int v0=dt*128, nb=b*NPG, eb=b*EPG, tid=threadIdx.x;
  for (int i=tid; i<66560/16; i+=512) ((uint4*)smem)[i]=(uint4){0u,0u,0u,0u};
  if (tid<128){
    isqs[tid]=in_isqrt[nb+v0+tid];
    if (L==1){ oscs[tid]=out_isqrt[nb+v0+tid]; bsh[tid]=bias[tid]; }
  }
  __syncthreads();
  {                                              // edge-parallel count scatter
    const int4* dv = (const int4*)(dst+eb);
    const int4* sv = (const int4*)(src+eb);
    #pragma unroll
    for (int j=0;j<4;j++){
      int4 d4 = dv[tid + j*512];
      int4 s4 = sv[tid + j*512];
      int dl, s;
      dl=(d4.x&(NPG-1))-v0; s=s4.x&(NPG-1);
      if ((unsigned)dl<128u) atomicAdd(&A32[dl*130+(s>>2)], 1u<<((s&3)*8));
      dl=(d4.y&(NPG-1))-v0; s=s4.y&(NPG-1);
      if ((unsigned)dl<128u) atomicAdd(&A32[dl*130+(s>>2)], 1u<<((s&3)*8));
      dl=(d4.z&(NPG-1))-v0; s=s4.z&(NPG-1);
      if ((unsigned)dl<128u) atomicAdd(&A32[dl*130+(s>>2)], 1u<<((s&3)*8));
      dl=(d4.w&(NPG-1))-v0; s=s4.w&(NPG-1);
      if ((unsigned)dl<128u) atomicAdd(&A32[dl*130+(s>>2)], 1u<<((s&3)*8));
    }
  }
  __syncthreads();
  const int wave=tid>>6, lane=tid&63, l16=lane&15, quad=lane>>4;
  const int mg=wave>>1, ng=wave&1;               // 8 m-tiles x 8 n-tiles total
  f32x4 acc[2][4];
  #pragma unroll
  for (int rt=0;rt<2;rt++)
    #pragma unroll
    for (int ct=0;ct<4;ct++) acc[rt][ct]=(f32x4){0.f,0.f,0.f,0.f};

  const unsigned short* hp[4];
  #pragma unroll
  for (int ct=0;ct<4;ct++)
    hp[ct] = feat + ((size_t)(b*128 + ng*64 + ct*16 + l16))*512 + quad*8;
  const unsigned char* Ab[2];
  #pragma unroll
  for (int rt=0;rt<2;rt++)
    Ab[rt] = A + ((mg*2+rt)*16 + l16)*520 + quad*8;

  // true ping-pong: load DIRECTLY into the buffer just consumed (no copies).
  uint4 hbuf[2][4];
  #pragma unroll
  for (int p=0;p<2;p++)
    #pragma unroll
    for (int ct=0;ct<4;ct++) hbuf[p][ct] = *(const uint4*)(hp[ct] + p*32);
  #pragma unroll
  for (int kk=0;kk<8;kk++){
    #pragma unroll
    for (int ph=0;ph<2;ph++){
      const int ks = kk*2 + ph;
      s16x8 afr[2];
      #pragma unroll
      for (int rt=0;rt<2;rt++){
        const uint2 aw = *(const uint2*)(Ab[rt] + ks*32);
        union { s16x8 v; unsigned short u[8]; } pk;
        #pragma unroll
        for (int j=0;j<4;j++){
          const float f0 = (float)((aw.x>>(8*j))&0xffu);   // exact small ints
          const float f1 = (float)((aw.y>>(8*j))&0xffu);
          pk.u[j]   = (unsigned short)(__builtin_bit_cast(unsigned int, f0)>>16);
          pk.u[j+4] = (unsigned short)(__builtin_bit_cast(unsigned int, f1)>>16);
        }
        afr[rt]=pk.v;
      }
      #pragma unroll
      for (int rt=0;rt<2;rt++)
        #pragma unroll
        for (int ct=0;ct<4;ct++)
          acc[rt][ct]=__builtin_amdgcn_mfma_f32_16x16x32_bf16(afr[rt],
              __builtin_bit_cast(s16x8, hbuf[ph][ct]), acc[rt][ct],0,0,0);
      const int kn = (ks+2<16)? (ks+2) : 15;     // clamped tail reload
      #pragma unroll
      for (int ct=0;ct<4;ct++) hbuf[ph][ct] = *(const uint4*)(hp[ct] + kn*32);
    }
  }
  #pragma unroll
  for (int rt=0;rt<2;rt++){
    const int mloc=(mg*2+rt)*16 + quad*4;
    #pragma unroll
    for (int ct=0;ct<4;ct++){
      const int col=ng*64 + ct*16 + l16;
      if (L==1){
        const float bb = bsh[col];
        ushort4 st;
        float v;
        v = fmaxf(acc[rt][ct][0]*isqs[mloc+0]+bb,0.f)*oscs[mloc+0]; st.x=f2bf(v);
        v = fmaxf(acc[rt][ct][1]*isqs[mloc+1]+bb,0.f)*oscs[mloc+1]; st.y=f2bf(v);
        v = fmaxf(acc[rt][ct][2]*isqs[mloc+2]+bb,0.f)*oscs[mloc+2]; st.z=f2bf(v);
        v = fmaxf(acc[rt][ct][3]*isqs[mloc+3]+bb,0.f)*oscs[mloc+3]; st.w=f2bf(v);
        *(ushort4*)(outp + ((size_t)(b*128+col))*512 + v0 + mloc) = st;
      } else {
        #pragma unroll
        for (int r=0;r<4;r++)
          outp[(size_t)(nb+v0+mloc+r)*128 + col] = f2bf(acc[rt][ct][r]*isqs[mloc+r]);
      }
    }
  }
}

// ---------- final GEMM: relu(M1 @ W2 + b2), fused per-graph mean -> out -----
__global__ __launch_bounds__(512) void k_gemm2(const unsigned short* __restrict__ M1,
      const float* __restrict__ W2, const float* __restrict__ b2,
      float* __restrict__ out){
  __shared__ __align__(16) unsigned short WT[128][136];  // WT[n][k]
  __shared__ float bsh[128];
  __shared__ float colpart[8][128];
  const int b=blockIdx.x, tid=threadIdx.x;
  for (int idx=tid; idx<128*128; idx+=512){
    const int k=idx>>7, n=idx&127;
    WT[n][k]=f2bf(W2[idx]);
  }
  if (tid<128) bsh[tid]=b2[tid];
  __syncthreads();
  const int wave=tid>>6, lane=tid&63, l16=lane&15, quad=lane>>4;
  float p[8];
  #pragma unroll
  for (int i=0;i<8;i++) p[i]=0.f;
  for (int chunk=0; chunk<2; ++chunk){
    const int rowbase = b*NPG + wave*64 + chunk*32;
    f32x4 acc[2][8];
    #pragma unroll
    for (int rt=0;rt<2;rt++)
      #pragma unroll
      for (int ct=0;ct<8;ct++) acc[rt][ct]=(f32x4){0.f,0.f,0.f,0.f};
    #pragma unroll
    for (int ks=0;ks<4;ks++){
      s16x8 a[2], bf[8];
      #pragma unroll
      for (int rt=0;rt<2;rt++){
        const unsigned short* ap = M1 + (size_t)(rowbase+rt*16+l16)*128 + ks*32 + quad*8;
        a[rt]=__builtin_bit_cast(s16x8, *(const uint4*)ap);
      }
      #pragma unroll
      for (int ct=0;ct<8;ct++)
        bf[ct]=__builtin_bit_cast(s16x8, *(const uint4*)&WT[ct*16+l16][ks*32+quad*8]);
      #pragma unroll
      for (int rt=0;rt<2;rt++)
        #pragma unroll
        for (int ct=0;ct<8;ct++)
          acc[rt][ct]=__builtin_amdgcn_mfma_f32_16x16x32_bf16(a[rt],bf[ct],acc[rt][ct],0,0,0);
    }
    #pragma unroll
    for (int rt=0;rt<2;rt++)
      #pragma unroll
      for (int ct=0;ct<8;ct++)
        #pragma unroll
        for (int r=0;r<4;r++){
          const int col=ct*16+l16;
          p[ct] += fmaxf(acc[rt][ct][r]+bsh[col],0.f);
        }
  }
  #pragma unroll
  for (int ct=0;ct<8;ct++){
    p[ct] += __shfl_xor(p[ct],16);
    p[ct] += __shfl_xor(p[ct],32);
  }
  if (quad==0){
    #pragma unroll
    for (int ct=0;ct<8;ct++) colpart[wave][ct*16+l16]=p[ct];
  }
  __syncthreads();
  if (tid<128){
    float s=0.f;
    #pragma unroll
    for (int w=0;w<8;w++) s+=colpart[w][tid];
    out[b*128+tid]=s*(1.f/512.f);
  }
}

extern "C" void kernel_launch(void* const* d_in, const int* in_sizes, int n_in,
                              void* d_out, int out_size, void* d_ws, size_t ws_size,
                              hipStream_t stream){
  const int* node_feat = (const int*)d_in[0];
  const int* src = (const int*)d_in[1];
  const int* dst = (const int*)d_in[2];
  const float* emb = (const float*)d_in[3];
  const float* W1  = (const float*)d_in[4];
  const float* b1  = (const float*)d_in[5];
  const float* W2  = (const float*)d_in[6];
  const float* b2  = (const float*)d_in[7];

  char* ws = (char*)d_ws;
  float* out_isqrt        = (float*)(ws);                          // 524288 B
  float* in_isqrt         = (float*)(ws + 524288);                 // 524288 B
  unsigned short* EW1T    = (unsigned short*)(ws + 1048576);       // 16384 B
  unsigned short* EW1R    = (unsigned short*)(ws + 1064960);       // 16384 B
  unsigned short* B1T     = (unsigned short*)(ws + 1081344);       // 33554432 B
  unsigned short* h1T     = (unsigned short*)(ws + 34635776);      // 33554432 B
  unsigned short* M1      = B1T;                                   // alias: B1T dead after agg1

  (void)hipFuncSetAttribute(reinterpret_cast<const void*>(&k_agg<1>),
        hipFuncAttributeMaxDynamicSharedMemorySize, AGG_LDS);
  (void)hipFuncSetAttribute(reinterpret_cast<const void*>(&k_agg<2>),
        hipFuncAttributeMaxDynamicSharedMemorySize, AGG_LDS);

  k_prep<<<32,256,0,stream>>>(emb,W1,EW1T,EW1R);
  k_deg<<<GRAPHS,512,0,stream>>>(src,dst,node_feat,EW1R,out_isqrt,in_isqrt,B1T);
  k_agg<1><<<GRAPHS*4,512,AGG_LDS,stream>>>(src,dst,B1T,in_isqrt,out_isqrt,b1,h1T);
  k_agg<2><<<GRAPHS*4,512,AGG_LDS,stream>>>(src,dst,h1T,in_isqrt,out_isqrt,b2,M1);
  k_gemm2<<<GRAPHS,512,0,stream>>>(M1,W2,b2,(float*)d_out);
}